// Round 2
// baseline (40587.408 us; speedup 1.0000x reference)
//
#include <hip/hip_runtime.h>
#include <cstddef>

#define B_ 128
#define S_ 512
#define I_ 1024
#define H_ 1024
#define G4_ 4096

// ---------------------------------------------------------------- zero init
__global__ __launch_bounds__(256) void k_zero(float* __restrict__ p, int n) {
  int i = blockIdx.x * 256 + threadIdx.x;
  if (i < n) p[i] = 0.0f;
}

// ---------------------------------------------------------------- big GEMM
// MODE 0: pre-GEMM. Chunk of Tc timesteps starting at t0.
//   C[tl*128 + b][4096] = x[b*512 + t0 + tl][1024] @ Wg_xpart + bias
//   grid = (32 n-tiles, T). Block by covers tl=by (all 128 b = tile rows).
// MODE 1: out-GEMM. C_out[(b*512+t0+by)] = hAllC[by*128+b][1024] @ Wout + bout
//   grid = (8, T).
// 128x128 tile, Ktile=32, 8x8 register tile, 256 threads.
template<int MODE>
__global__ __launch_bounds__(256) void k_gemm(
    const float* __restrict__ A,
    const float* __restrict__ W0, const float* __restrict__ W1,
    const float* __restrict__ W2, const float* __restrict__ W3,
    const float* __restrict__ bb0, const float* __restrict__ bb1,
    const float* __restrict__ bb2, const float* __restrict__ bb3,
    float* __restrict__ C, int t0)
{
  __shared__ float As[32 * 128];   // A tile, transposed [k][m]
  __shared__ float Bs[32 * 128];   // B tile, [k][n]
  const int tid = threadIdx.x;
  const int n0g = blockIdx.x * 128;
  const int by  = blockIdx.y;

  const float* Bmat;
  const float* bias;
  int g = 0, j0c = 0;
  if (MODE == 0) {
    g   = n0g >> 10;        // gate 0..3; 128 | 1024 so tile never straddles
    j0c = n0g & 1023;
    Bmat = ((g == 0) ? W0 : (g == 1) ? W1 : (g == 2) ? W2 : W3) + j0c;
    bias = ((g == 0) ? bb0 : (g == 1) ? bb1 : (g == 2) ? bb2 : bb3) + j0c;
  } else {
    Bmat = W0 + n0g;
    bias = bb0 + n0g;
  }

  const int tx = tid & 15, ty = tid >> 4;
  float acc[8][8];
#pragma unroll
  for (int i = 0; i < 8; ++i)
#pragma unroll
    for (int jq = 0; jq < 8; ++jq) acc[i][jq] = 0.0f;

  const int afr = tid & 7,  arow = tid >> 3;   // A staging: 8 float4 per k-row
  const int bnb = tid & 31, bkk  = tid >> 5;   // B staging

  for (int k0 = 0; k0 < 1024; k0 += 32) {
#pragma unroll
    for (int rr = 0; rr < 4; ++rr) {
      const int r = rr * 32 + arow;            // tile row = b (MODE0) / m (MODE1)
      size_t arowoff;
      if (MODE == 0) arowoff = ((size_t)r * 512 + (size_t)(t0 + by)) * 1024;
      else           arowoff = (size_t)(by * 128 + r) * 1024;
      const float4 v = *(const float4*)(A + arowoff + k0 + afr * 4);
      As[(afr * 4 + 0) * 128 + r] = v.x;
      As[(afr * 4 + 1) * 128 + r] = v.y;
      As[(afr * 4 + 2) * 128 + r] = v.z;
      As[(afr * 4 + 3) * 128 + r] = v.w;
    }
#pragma unroll
    for (int rr = 0; rr < 4; ++rr) {
      const int r = rr * 8 + bkk;
      *(float4*)(Bs + r * 128 + bnb * 4) =
          *(const float4*)(Bmat + (size_t)(k0 + r) * 1024 + bnb * 4);
    }
    __syncthreads();
#pragma unroll
    for (int kk = 0; kk < 32; ++kk) {
      const float4 a0 = *(const float4*)(As + kk * 128 + ty * 8);
      const float4 a1 = *(const float4*)(As + kk * 128 + ty * 8 + 4);
      const float4 w0 = *(const float4*)(Bs + kk * 128 + tx * 8);
      const float4 w1 = *(const float4*)(Bs + kk * 128 + tx * 8 + 4);
      const float av[8] = {a0.x, a0.y, a0.z, a0.w, a1.x, a1.y, a1.z, a1.w};
      const float wv[8] = {w0.x, w0.y, w0.z, w0.w, w1.x, w1.y, w1.z, w1.w};
#pragma unroll
      for (int i = 0; i < 8; ++i)
#pragma unroll
        for (int jq = 0; jq < 8; ++jq)
          acc[i][jq] = fmaf(av[i], wv[jq], acc[i][jq]);
    }
    __syncthreads();
  }

  float bv[8];
#pragma unroll
  for (int jq = 0; jq < 8; ++jq) bv[jq] = bias[tx * 8 + jq];

#pragma unroll
  for (int i = 0; i < 8; ++i) {
    const int r = ty * 8 + i;       // = b in both modes
    float* crow;
    if (MODE == 0) {
      crow = C + ((size_t)by * 128 + r) * G4_ + (size_t)g * 1024 + j0c + tx * 8;
    } else {
      crow = C + ((size_t)r * 512 + (size_t)(t0 + by)) * 1024 + n0g + tx * 8;
    }
    float4 o0, o1;
    o0.x = acc[i][0] + bv[0]; o0.y = acc[i][1] + bv[1];
    o0.z = acc[i][2] + bv[2]; o0.w = acc[i][3] + bv[3];
    o1.x = acc[i][4] + bv[4]; o1.y = acc[i][5] + bv[5];
    o1.z = acc[i][6] + bv[6]; o1.w = acc[i][7] + bv[7];
    *(float4*)crow       = o0;
    *(float4*)(crow + 4) = o1;
  }
}

// ---------------------------------------------------------------- scan step
// 256 blocks; block owns 4 hidden columns j0..j0+3 x 4 gates (16 gc), all 128 b.
// LDS: W slice only, [1024 k][16 gc] fp32 = 65536 B exactly, gc = g*4+jj with
// kq-rotation swizzle so the 4 K-split groups read disjoint bank phases.
// GEMM: wave w owns 32 b; lane = kq(2b)*16 + bq; thread: 2b x 16gc acc over
// K-range 256. Reduce via __shfl_xor(16/32). Epilogue fused state update.
__global__ __launch_bounds__(256) void k_step(
    const float* __restrict__ Wf, const float* __restrict__ Wi,
    const float* __restrict__ Wc, const float* __restrict__ Wo,
    const float* __restrict__ preC,      // [Tc][128][4096]
    const float* __restrict__ hT_in,     // [1024 j][128 b]
    float* __restrict__ hT_out,
    float* __restrict__ cb, float* __restrict__ nb, float* __restrict__ mb,
    float* __restrict__ hAllC,           // [Tc*128][1024]
    int t_local)
{
  __shared__ float Wl[1024 * 16];        // 65536 B
  const int tid = threadIdx.x;
  const int j0  = blockIdx.x * 4;

  // ---- stage W h-part slice ----
#pragma unroll
  for (int r = 0; r < 16; ++r) {
    const int gk = r * 256 + tid;        // [0,4096)
    const int g = gk & 3, k = gk >> 2;
    const float* Wg = (g == 0) ? Wf : (g == 1) ? Wi : (g == 2) ? Wc : Wo;
    const float4 v = *(const float4*)(Wg + (size_t)(I_ + k) * H_ + j0);
    const int rot = (g + (k >> 8)) & 3;  // bank-phase rotation per K-range
    *(float4*)(&Wl[k * 16 + rot * 4]) = v;
  }
  __syncthreads();

  const int w    = tid >> 6;             // wave 0..3
  const int lane = tid & 63;
  const int bq   = lane & 15;
  const int kq   = lane >> 4;            // K-split 0..3
  const int b0   = w * 32 + bq * 2;

  float acc[2][16];
#pragma unroll
  for (int ib = 0; ib < 2; ++ib)
#pragma unroll
    for (int c = 0; c < 16; ++c) acc[ib][c] = 0.0f;

  const int r0 = ((0 + kq) & 3) * 4;     // per-thread rotated g offsets
  const int r1 = ((1 + kq) & 3) * 4;
  const int r2 = ((2 + kq) & 3) * 4;
  const int r3 = ((3 + kq) & 3) * 4;
  const int kbase = kq * 256;

#pragma unroll 2
  for (int ki = 0; ki < 256; ++ki) {
    const int k = kbase + ki;
    const float2 h2 = *(const float2*)(hT_in + (size_t)k * 128 + b0);
    const float4 w0 = *(const float4*)(&Wl[k * 16 + r0]);   // gate f, jj 0..3
    const float4 w1 = *(const float4*)(&Wl[k * 16 + r1]);   // gate i
    const float4 w2 = *(const float4*)(&Wl[k * 16 + r2]);   // gate c
    const float4 w3 = *(const float4*)(&Wl[k * 16 + r3]);   // gate o
    const float wv[16] = {w0.x, w0.y, w0.z, w0.w, w1.x, w1.y, w1.z, w1.w,
                          w2.x, w2.y, w2.z, w2.w, w3.x, w3.y, w3.z, w3.w};
#pragma unroll
    for (int c = 0; c < 16; ++c) {
      acc[0][c] = fmaf(h2.x, wv[c], acc[0][c]);
      acc[1][c] = fmaf(h2.y, wv[c], acc[1][c]);
    }
  }
  __syncthreads();     // all waves done reading Wl

  // ---- restage pre slice into dead Wl region: [128 b][g*4+jj] ----
  const float* pre_t = preC + (size_t)t_local * (128 * 4096);
#pragma unroll
  for (int r = 0; r < 2; ++r) {
    const int id = r * 256 + tid;        // [0,512): g = id&3, b = id>>2
    const int g = id & 3, b = id >> 2;
    const float4 v = *(const float4*)(pre_t + (size_t)b * 4096 + g * 1024 + j0);
    *(float4*)(&Wl[b * 16 + g * 4]) = v;
  }

  // ---- shuffle reduce over kq (overlaps pre staging) ----
#pragma unroll
  for (int ib = 0; ib < 2; ++ib)
#pragma unroll
    for (int c = 0; c < 16; ++c) {
      float v = acc[ib][c];
      v += __shfl_xor(v, 16);
      v += __shfl_xor(v, 32);
      acc[ib][c] = v;
    }
  __syncthreads();     // preL visible

  // ---- fused elementwise update (lanes kq==0 hold full sums) ----
  if (kq == 0) {
#pragma unroll
    for (int ib = 0; ib < 2; ++ib) {
      const int b = b0 + ib;
#pragma unroll
      for (int jj = 0; jj < 4; ++jj) {
        const int j = j0 + jj;
        const float f_log = acc[ib][0  + jj] + Wl[b * 16 + 0  + jj];
        const float i_log = acc[ib][4  + jj] + Wl[b * 16 + 4  + jj];
        const float c_log = acc[ib][8  + jj] + Wl[b * 16 + 8  + jj];
        const float o_log = acc[ib][12 + jj] + Wl[b * 16 + 12 + jj];

        const int sIdx = j * 128 + b;
        const float m_old = mb[sIdx];
        const float c_old = cb[sIdx];
        const float n_old = nb[sIdx];

        const float m_new = fmaxf(f_log + m_old, i_log);
        const float i_t   = expf(i_log - m_new);
        const float f_t   = expf(f_log + m_old - m_new);
        const float c_hat = tanhf(c_log);
        const float o_t   = 1.0f / (1.0f + expf(-o_log));
        const float c_new = f_t * c_old + i_t * c_hat;
        const float n_new = f_t * n_old + i_t;
        const float h_new = o_t * (c_new / (n_new + 1e-8f));

        cb[sIdx] = c_new;
        nb[sIdx] = n_new;
        mb[sIdx] = m_new;
        hT_out[sIdx] = h_new;                                    // [j][b]
        hAllC[((size_t)t_local * 128 + b) * 1024 + j] = h_new;   // chunk rows
      }
    }
  }
}

// ---------------------------------------------------------------- final state tail
__global__ __launch_bounds__(256) void k_tail(
    const float* __restrict__ hT, const float* __restrict__ cbp,
    const float* __restrict__ nbp, const float* __restrict__ mbp,
    float* __restrict__ dst)
{
  const int gid = blockIdx.x * 256 + threadIdx.x;   // [0, 4*131072)
  const int q = gid >> 17, rem = gid & 131071;
  const int b = rem >> 10, j = rem & 1023;
  const float* src = (q == 0) ? hT : (q == 1) ? cbp : (q == 2) ? nbp : mbp;
  dst[gid] = src[j * B_ + b];
}

// ---------------------------------------------------------------- launch
extern "C" void kernel_launch(void* const* d_in, const int* in_sizes, int n_in,
                              void* d_out, int out_size, void* d_ws, size_t ws_size,
                              hipStream_t stream) {
  const float* x    = (const float*)d_in[0];
  const float* Wf   = (const float*)d_in[1];
  const float* bfv  = (const float*)d_in[2];
  const float* Wi   = (const float*)d_in[3];
  const float* biv  = (const float*)d_in[4];
  const float* Wc   = (const float*)d_in[5];
  const float* bcv  = (const float*)d_in[6];
  const float* Wo   = (const float*)d_in[7];
  const float* bov  = (const float*)d_in[8];
  const float* Wout = (const float*)d_in[9];
  const float* bout = (const float*)d_in[10];
  float* out = (float*)d_out;

  // workspace layout: states first, then chunk buffers sized to fit ws_size
  float* hT0 = (float*)d_ws;
  float* hT1 = hT0 + 131072;
  float* cb  = hT0 + 2 * 131072;
  float* nb  = hT0 + 3 * 131072;
  float* mb  = hT0 + 4 * 131072;
  float* chunk0 = hT0 + 5 * 131072;

  const size_t stateBytes = (size_t)5 * 131072 * sizeof(float);
  const size_t perT = ((size_t)128 * 4096 + (size_t)128 * 1024) * sizeof(float); // 2.5 MiB/step
  const size_t avail = (ws_size > stateBytes) ? (ws_size - stateBytes) : 0;
  int Tc = (int)(avail / perT);
  if (Tc > S_) Tc = S_;
  if (Tc < 1)  Tc = 1;     // below ~5 MiB ws nothing fits; best effort

  float* preC  = chunk0;                          // [Tc][128][4096]
  float* hAllC = preC + (size_t)Tc * 128 * 4096;  // [Tc*128][1024]

  // zero h, c, n, m (ws is poisoned 0xAA every call)
  k_zero<<<2560, 256, 0, stream>>>(hT0, 5 * 131072);

  for (int t0 = 0; t0 < S_; t0 += Tc) {
    const int T = (S_ - t0 < Tc) ? (S_ - t0) : Tc;

    // pre-gates for this chunk: x-part of all 4 gate GEMMs + bias
    k_gemm<0><<<dim3(32, T), 256, 0, stream>>>(x, Wf, Wi, Wc, Wo,
                                               bfv, biv, bcv, bov, preC, t0);
    // sequential scan over the chunk
    for (int tl = 0; tl < T; ++tl) {
      const int tg = t0 + tl;
      const float* hin = (tg & 1) ? hT1 : hT0;
      float* hout      = (tg & 1) ? hT0 : hT1;
      k_step<<<256, 256, 0, stream>>>(Wf, Wi, Wc, Wo, preC, hin, hout,
                                      cb, nb, mb, hAllC, tl);
    }
    // outputs for this chunk: hAllC @ Wout + bout
    k_gemm<1><<<dim3(8, T), 256, 0, stream>>>(hAllC, Wout, Wout, Wout, Wout,
                                              bout, bout, bout, bout, out, t0);
  }

  // final h, c, n, m (h ends in hT0 after 512 steps)
  k_tail<<<2048, 256, 0, stream>>>(hT0, cb, nb, mb, out + (size_t)B_ * S_ * H_);
}